// Round 7
// baseline (1178.055 us; speedup 1.0000x reference)
//
#include <hip/hip_runtime.h>
#include <hip/hip_fp16.h>
#include <math.h>

#define N_NODES 50000
#define N_EDGES 800000
#define E2 (N_EDGES + N_NODES)   // 850000
#define HEADS 5
#define C1 32
#define F1 160

// bucket CSR build: 64-node buckets
#define BSZ 64
#define NBK 782                  // 782*64 = 50048 >= N
#define NBL 208                  // edge-chunk blocks
#define CH  4087                 // 208*4087 = 850096 >= E2
#define MTOT (NBK*NBL)           // 162656
#define MC  636                  // ceil(MTOT/256)

static constexpr size_t alignup(size_t x){ return (x + 255) & ~size_t(255); }
static constexpr size_t OFF_SCAL  = 0;                                           // 64 f
static constexpr size_t OFF_H     = alignup(OFF_SCAL + 64*4);                    // MTOT i
static constexpr size_t OFF_PART  = alignup(OFF_H    + (size_t)MTOT*4);          // MC
static constexpr size_t OFF_PPREF = alignup(OFF_PART + (size_t)MC*4);            // MC
static constexpr size_t OFF_BST   = alignup(OFF_PPREF+ (size_t)MC*4);            // NBK+1
static constexpr size_t OFF_BPACK = alignup(OFF_BST  + (size_t)(NBK+1)*4);       // E2 int2
static constexpr size_t OFF_AS1P  = alignup(OFF_BPACK+ (size_t)E2*8);            // N*8 f
static constexpr size_t OFF_AD1P  = alignup(OFF_AS1P + (size_t)N_NODES*8*4);     // N*8 f
static constexpr size_t OFF_G2    = alignup(OFF_AD1P + (size_t)N_NODES*8*4);     // N*16 f (64B/node)
static constexpr size_t OFF_AD2P  = alignup(OFF_G2   + (size_t)N_NODES*16*4);    // N*8 f
static constexpr size_t OFF_H1H   = alignup(OFF_AD2P + (size_t)N_NODES*8*4);     // N*160 half
static constexpr size_t OFF_X2H   = alignup(OFF_H1H  + (size_t)N_NODES*F1*2);    // N*160 half

// ---- pass 1: LDS coarse histogram (64-node buckets) + ea sum ----
__global__ __launch_bounds__(256) void k_hist(const int* __restrict__ dst, const float* __restrict__ ea,
                       int* __restrict__ H, float* __restrict__ scal){
  __shared__ int hist[NBK];
  for (int k = threadIdx.x; k < NBK; k += 256) hist[k] = 0;
  __syncthreads();
  int b = blockIdx.x;
  int e0 = b*CH, e1 = min(e0 + CH, E2);
  float s = 0.f;
  for (int e = e0 + threadIdx.x; e < e1; e += 256){
    int d;
    if (e < N_EDGES){ d = dst[e]; s += ea[e]; }
    else d = e - N_EDGES;
    atomicAdd(&hist[d >> 6], 1);
  }
  __syncthreads();
  for (int k = threadIdx.x; k < NBK; k += 256) H[(size_t)k*NBL + b] = hist[k];
  #pragma unroll
  for (int m = 1; m < 64; m <<= 1) s += __shfl_xor(s, m, 64);
  if ((threadIdx.x & 63) == 0) atomicAdd(scal, s);
}

// scal[0]=sum_ea, scal[1]=mean_ea, scal[2..6]=wedot1[h], scal[7..11]=wedot2[h]
__global__ void k_prep(const float* __restrict__ We1, const float* __restrict__ ae1,
                       const float* __restrict__ We2, const float* __restrict__ ae2,
                       float* __restrict__ scal){
  int t = threadIdx.x;
  if (t == 0) scal[1] = scal[0] / (float)N_EDGES;
  if (t < HEADS){
    float s = 0.f;
    for (int c = 0; c < C1; c++) s += We1[t*C1 + c] * ae1[t*C1 + c];
    scal[2 + t] = s;
    scal[7 + t] = We2[t] * ae2[t];
  }
}

// ---- scan of H ----
__global__ void k_s1(const int* __restrict__ H, int* __restrict__ partial){
  int i = blockIdx.x*256 + threadIdx.x;
  int v = (i < MTOT) ? H[i] : 0;
  #pragma unroll
  for (int m = 1; m < 64; m <<= 1) v += __shfl_xor(v, m, 64);
  __shared__ int sh[4];
  if ((threadIdx.x & 63) == 0) sh[threadIdx.x >> 6] = v;
  __syncthreads();
  if (threadIdx.x == 0) partial[blockIdx.x] = sh[0] + sh[1] + sh[2] + sh[3];
}

__global__ __launch_bounds__(1024) void k_s2(const int* __restrict__ partial, int* __restrict__ ppref,
                      int* __restrict__ bstart){
  __shared__ int sp[1024];
  int t = threadIdx.x;
  int v = (t < MC) ? partial[t] : 0;
  sp[t] = v;
  __syncthreads();
  for (int off = 1; off < 1024; off <<= 1){
    int u = (t >= off) ? sp[t - off] : 0;
    __syncthreads();
    sp[t] += u;
    __syncthreads();
  }
  if (t < MC) ppref[t] = sp[t] - v;
  if (t == 0) bstart[NBK] = E2;
}

__global__ void k_s3(int* __restrict__ H, const int* __restrict__ ppref, int* __restrict__ bstart){
  __shared__ int sp[256];
  int b = blockIdx.x, t = threadIdx.x;
  int i = b*256 + t;
  int v = (i < MTOT) ? H[i] : 0;
  sp[t] = v;
  __syncthreads();
  for (int off = 1; off < 256; off <<= 1){
    int u = (t >= off) ? sp[t - off] : 0;
    __syncthreads();
    sp[t] += u;
    __syncthreads();
  }
  int P = ppref[b] + sp[t] - v;
  if (i < MTOT){
    H[i] = P;
    if (i % NBL == 0) bstart[i / NBL] = P;
  }
}

// ---- pass 2: scatter into bucket-major packed records (8B/edge) ----
__global__ __launch_bounds__(256) void k_scat(const int* __restrict__ src, const int* __restrict__ dst,
                       const float* __restrict__ ea, const float* __restrict__ scal,
                       const int* __restrict__ H, int2* __restrict__ bpack){
  __shared__ int lofs[NBK];
  int b = blockIdx.x;
  for (int k = threadIdx.x; k < NBK; k += 256) lofs[k] = H[(size_t)k*NBL + b];
  __syncthreads();
  float mean = scal[1];
  int e0 = b*CH, e1 = min(e0 + CH, E2);
  for (int e = e0 + threadIdx.x; e < e1; e += 256){
    int d, s; float a;
    if (e < N_EDGES){ d = dst[e]; s = src[e]; a = ea[e]; }
    else { d = s = e - N_EDGES; a = mean; }
    int pos = atomicAdd(&lofs[d >> 6], 1);
    bpack[pos] = make_int2(s | ((d & 63) << 16), __float_as_int(a));
  }
}

// ---- layer 1: h1h(fp16) = x@W1, as1p/ad1p (padded 8) ----
__global__ __launch_bounds__(320) void k_h1(const float* __restrict__ x, const float* __restrict__ W1,
                    const float* __restrict__ as1w, const float* __restrict__ ad1w,
                    __half* __restrict__ h1h, float* __restrict__ as1p, float* __restrict__ ad1p){
  __shared__ float sW[5*F1];
  for (int k = threadIdx.x; k < 5*F1; k += 320) sW[k] = W1[k];
  __syncthreads();
  int nl = threadIdx.x / 80;
  int c  = threadIdx.x - nl*80;
  int n  = blockIdx.x*4 + nl;
  int c0 = 2*c;
  float hv0 = 0.f, hv1 = 0.f;
  #pragma unroll
  for (int f = 0; f < 5; f++){
    float xv = x[n*5 + f];
    hv0 += xv * sW[f*F1 + c0];
    hv1 += xv * sW[f*F1 + c0 + 1];
  }
  ((__half2*)h1h)[n*80 + c] = __floats2half2_rn(hv0, hv1);
  float vs = hv0*as1w[c0] + hv1*as1w[c0+1];
  float vd = hv0*ad1w[c0] + hv1*ad1w[c0+1];
  #pragma unroll
  for (int m = 8; m >= 1; m >>= 1){
    vs += __shfl_xor(vs, m, 64);
    vd += __shfl_xor(vd, m, 64);
  }
  if ((c & 15) == 0){
    int h = c >> 4;
    as1p[n*8 + h] = vs;
    ad1p[n*8 + h] = vd;
  }
}

// ---- fused layer-1 softmax + aggregate, bucket-major (block per 64-node bucket) ----
__global__ __launch_bounds__(320) void k_bagg1(const int* __restrict__ bstart, const int2* __restrict__ bpack,
                        const float* __restrict__ as1p, const float* __restrict__ ad1p,
                        const float* __restrict__ scal, const __half* __restrict__ h1h,
                        const float* __restrict__ b1, __half* __restrict__ x2h){
  __shared__ float accL[BSZ*F1];       // 40 KB
  __shared__ float denL[BSZ*HEADS];
  __shared__ float adL [BSZ*HEADS];
  int k = blockIdx.x, t = threadIdx.x;
  int base = k*BSZ;
  for (int i = t; i < BSZ*HEADS; i += 320){
    int node = base + i/HEADS;
    adL[i] = (node < N_NODES) ? ad1p[node*8 + i%HEADS] : 0.f;
    denL[i] = 0.f;
  }
  for (int i = t; i < BSZ*F1; i += 320) accL[i] = 0.f;
  __syncthreads();
  int g = t / 80, c = t - g*80, h = c >> 4;
  float wd = scal[2 + h];
  const __half2* h12 = (const __half2*)h1h;
  int r0 = bstart[k], r1 = bstart[k + 1];
  for (int e0 = r0 + g; e0 < r1; e0 += 16){
    int ee0 = e0, ee1 = e0 + 4, ee2 = e0 + 8, ee3 = e0 + 12;
    int2 pk0 = (ee0 < r1) ? bpack[ee0] : make_int2(0, 0);
    int2 pk1 = (ee1 < r1) ? bpack[ee1] : make_int2(0, 0);
    int2 pk2 = (ee2 < r1) ? bpack[ee2] : make_int2(0, 0);
    int2 pk3 = (ee3 < r1) ? bpack[ee3] : make_int2(0, 0);
    int s0 = pk0.x & 0xFFFF, s1 = pk1.x & 0xFFFF, s2 = pk2.x & 0xFFFF, s3 = pk3.x & 0xFFFF;
    __half2 f0 = h12[(size_t)s0*80 + c];
    __half2 f1 = h12[(size_t)s1*80 + c];
    __half2 f2 = h12[(size_t)s2*80 + c];
    __half2 f3 = h12[(size_t)s3*80 + c];
    float g0 = as1p[s0*8 + h], g1 = as1p[s1*8 + h];
    float g2 = as1p[s2*8 + h], g3 = as1p[s3*8 + h];
    int d0 = (pk0.x >> 16) & 63, d1 = (pk1.x >> 16) & 63;
    int d2 = (pk2.x >> 16) & 63, d3 = (pk3.x >> 16) & 63;
    float l0 = g0 + adL[d0*HEADS + h] + __int_as_float(pk0.y)*wd;
    float l1 = g1 + adL[d1*HEADS + h] + __int_as_float(pk1.y)*wd;
    float l2 = g2 + adL[d2*HEADS + h] + __int_as_float(pk2.y)*wd;
    float l3 = g3 + adL[d3*HEADS + h] + __int_as_float(pk3.y)*wd;
    l0 = fmaxf(l0, 0.2f*l0); l1 = fmaxf(l1, 0.2f*l1);
    l2 = fmaxf(l2, 0.2f*l2); l3 = fmaxf(l3, 0.2f*l3);
    float p0 = (ee0 < r1) ? __expf(l0) : 0.f;
    float p1 = (ee1 < r1) ? __expf(l1) : 0.f;
    float p2 = (ee2 < r1) ? __expf(l2) : 0.f;
    float p3 = (ee3 < r1) ? __expf(l3) : 0.f;
    float2 q0 = __half22float2(f0), q1 = __half22float2(f1);
    float2 q2 = __half22float2(f2), q3 = __half22float2(f3);
    atomicAdd(&accL[d0*F1 + 2*c],     p0*q0.x);
    atomicAdd(&accL[d0*F1 + 2*c + 1], p0*q0.y);
    atomicAdd(&accL[d1*F1 + 2*c],     p1*q1.x);
    atomicAdd(&accL[d1*F1 + 2*c + 1], p1*q1.y);
    atomicAdd(&accL[d2*F1 + 2*c],     p2*q2.x);
    atomicAdd(&accL[d2*F1 + 2*c + 1], p2*q2.y);
    atomicAdd(&accL[d3*F1 + 2*c],     p3*q3.x);
    atomicAdd(&accL[d3*F1 + 2*c + 1], p3*q3.y);
    if ((c & 15) == 0){
      atomicAdd(&denL[d0*HEADS + h], p0);
      atomicAdd(&denL[d1*HEADS + h], p1);
      atomicAdd(&denL[d2*HEADS + h], p2);
      atomicAdd(&denL[d3*HEADS + h], p3);
    }
  }
  __syncthreads();
  for (int i = t; i < BSZ*80; i += 320){
    int node = i / 80, cp = i - node*80;
    int n = base + node;
    if (n < N_NODES){
      int hh = cp >> 4;
      float inv = 1.f / (denL[node*HEADS + hh] + 1e-16f);
      float v0 = accL[node*F1 + 2*cp]*inv     + b1[2*cp];
      float v1 = accL[node*F1 + 2*cp + 1]*inv + b1[2*cp + 1];
      v0 = fmaxf(v0, 0.f); v1 = fmaxf(v1, 0.f);
      ((__half2*)x2h)[(size_t)n*80 + cp] = __floats2half2_rn(v0, v1);
    }
  }
}

// ---- layer 2: h2 = x2h@W2; write packed G[n*16]: [0..4]=h2, [8..12]=as2; ad2p separate ----
__global__ __launch_bounds__(256) void k_h2(const __half* __restrict__ x2h, const float* __restrict__ W2,
                    const float* __restrict__ asw2, const float* __restrict__ adw2,
                    float* __restrict__ G, float* __restrict__ ad2p){
  __shared__ float sW[F1*HEADS];
  for (int k = threadIdx.x; k < F1*HEADS; k += 256) sW[k] = W2[k];
  __syncthreads();
  int w = threadIdx.x >> 6, l = threadIdx.x & 63;
  int n = blockIdx.x*4 + w;
  const __half2* x22 = (const __half2*)x2h;
  float acc[HEADS] = {0.f, 0.f, 0.f, 0.f, 0.f};
  for (int k2 = l; k2 < 80; k2 += 64){
    float2 f = __half22float2(x22[n*80 + k2]);
    #pragma unroll
    for (int h = 0; h < HEADS; h++)
      acc[h] += f.x * sW[(2*k2)*HEADS + h] + f.y * sW[(2*k2+1)*HEADS + h];
  }
  #pragma unroll
  for (int m = 1; m < 64; m <<= 1){
    #pragma unroll
    for (int h = 0; h < HEADS; h++) acc[h] += __shfl_xor(acc[h], m, 64);
  }
  if (l == 0){
    #pragma unroll
    for (int h = 0; h < HEADS; h++){
      G[(size_t)n*16 + h]     = acc[h];
      G[(size_t)n*16 + 8 + h] = acc[h] * asw2[h];
      ad2p[n*8 + h]           = acc[h] * adw2[h];
    }
  }
}

// ---- fused layer-2 softmax + aggregate + mean + linear + sigmoid, bucket-major ----
__global__ __launch_bounds__(256) void k_bagg2(const int* __restrict__ bstart, const int2* __restrict__ bpack,
                        const float* __restrict__ G, const float* __restrict__ ad2p,
                        const float* __restrict__ scal, const float* __restrict__ b2,
                        const float* __restrict__ Wlin, float* __restrict__ out){
  __shared__ float acL[BSZ*HEADS], dnL[BSZ*HEADS], adL[BSZ*HEADS];
  int k = blockIdx.x, t = threadIdx.x, base = k*BSZ;
  for (int i = t; i < BSZ*HEADS; i += 256){   // FIX: was `if (t < BSZ*HEADS)` with 320>256
    int node = base + i/HEADS;
    adL[i] = (node < N_NODES) ? ad2p[node*8 + i%HEADS] : 0.f;
    acL[i] = 0.f; dnL[i] = 0.f;
  }
  __syncthreads();
  float wd[HEADS];
  #pragma unroll
  for (int h = 0; h < HEADS; h++) wd[h] = scal[7 + h];
  int r0 = bstart[k], r1 = bstart[k + 1];
  for (int e = r0 + t; e < r1; e += 256){
    int2 pk = bpack[e];
    int s = pk.x & 0xFFFF, dloc = (pk.x >> 16) & 63;
    float ea = __int_as_float(pk.y);
    const float* gs = G + (size_t)s*16;
    float4 h4 = *(const float4*)gs;        float h5v = gs[4];
    float4 a4 = *(const float4*)(gs + 8);  float a5v = gs[12];
    float hv[HEADS] = {h4.x, h4.y, h4.z, h4.w, h5v};
    float av[HEADS] = {a4.x, a4.y, a4.z, a4.w, a5v};
    #pragma unroll
    for (int h = 0; h < HEADS; h++){
      float lg = av[h] + adL[dloc*HEADS + h] + ea*wd[h];
      lg = fmaxf(lg, 0.2f*lg);
      float p = __expf(lg);
      atomicAdd(&dnL[dloc*HEADS + h], p);
      atomicAdd(&acL[dloc*HEADS + h], p*hv[h]);
    }
  }
  __syncthreads();
  if (t < BSZ){
    int n = base + t;
    if (n < N_NODES){
      float v = 0.f;
      #pragma unroll
      for (int h = 0; h < HEADS; h++) v += acL[t*HEADS + h] / (dnL[t*HEADS + h] + 1e-16f);
      v = v * (1.f/HEADS) + b2[0];
      v *= Wlin[0];
      out[n] = 1.f / (1.f + __expf(-v));
    }
  }
}

extern "C" void kernel_launch(void* const* d_in, const int* in_sizes, int n_in,
                              void* d_out, int out_size, void* d_ws, size_t ws_size,
                              hipStream_t stream) {
  const float* x    = (const float*)d_in[0];
  const float* ea   = (const float*)d_in[1];
  const int*   src  = (const int*)d_in[2];
  const int*   dst  = (const int*)d_in[3];
  const float* W1   = (const float*)d_in[4];
  const float* as1w = (const float*)d_in[5];
  const float* ad1w = (const float*)d_in[6];
  const float* We1  = (const float*)d_in[7];
  const float* ae1  = (const float*)d_in[8];
  const float* b1   = (const float*)d_in[9];
  const float* W2   = (const float*)d_in[10];
  const float* as2w = (const float*)d_in[11];
  const float* ad2w = (const float*)d_in[12];
  const float* We2  = (const float*)d_in[13];
  const float* ae2  = (const float*)d_in[14];
  const float* b2   = (const float*)d_in[15];
  const float* Wlin = (const float*)d_in[16];

  char* ws = (char*)d_ws;
  float* scal   = (float*)(ws + OFF_SCAL);
  int*   H      = (int*)  (ws + OFF_H);
  int*   part   = (int*)  (ws + OFF_PART);
  int*   ppref  = (int*)  (ws + OFF_PPREF);
  int*   bstart = (int*)  (ws + OFF_BST);
  int2*  bpack  = (int2*) (ws + OFF_BPACK);
  float* as1p   = (float*)(ws + OFF_AS1P);
  float* ad1p   = (float*)(ws + OFF_AD1P);
  float* G      = (float*)(ws + OFF_G2);
  float* ad2p   = (float*)(ws + OFF_AD2P);
  __half* h1h   = (__half*)(ws + OFF_H1H);
  __half* x2h   = (__half*)(ws + OFF_X2H);
  float* outp   = (float*)d_out;

  hipMemsetAsync(scal, 0, 64*sizeof(float), stream);

  k_h1    <<<N_NODES/4, 320, 0, stream>>>(x, W1, as1w, ad1w, h1h, as1p, ad1p);
  k_hist  <<<NBL, 256, 0, stream>>>(dst, ea, H, scal);
  k_prep  <<<1, 64, 0, stream>>>(We1, ae1, We2, ae2, scal);
  k_s1    <<<MC, 256, 0, stream>>>(H, part);
  k_s2    <<<1, 1024, 0, stream>>>(part, ppref, bstart);
  k_s3    <<<MC, 256, 0, stream>>>(H, ppref, bstart);
  k_scat  <<<NBL, 256, 0, stream>>>(src, dst, ea, scal, H, bpack);

  k_bagg1 <<<NBK, 320, 0, stream>>>(bstart, bpack, as1p, ad1p, scal, h1h, b1, x2h);
  k_h2    <<<N_NODES/4, 256, 0, stream>>>(x2h, W2, as2w, ad2w, G, ad2p);
  k_bagg2 <<<NBK, 256, 0, stream>>>(bstart, bpack, G, ad2p, scal, b2, Wlin, outp);
}

// Round 8
// 413.788 us; speedup vs baseline: 2.8470x; 2.8470x over previous
//
#include <hip/hip_runtime.h>
#include <hip/hip_fp16.h>
#include <math.h>

#define N_NODES 50000
#define N_EDGES 800000
#define E2 (N_EDGES + N_NODES)   // 850000
#define HEADS 5
#define C1 32
#define F1 160

// counting-sort CSR build (128-node buckets) — R5-proven constants
#define NBK 391
#define NBL 416
#define CH  2044                 // 416*2044 >= E2
#define MTOT (NBK*NBL)           // 162656
#define MC  636                  // ceil(MTOT/256)

static constexpr size_t alignup(size_t x){ return (x + 255) & ~size_t(255); }
static constexpr size_t OFF_SCAL  = 0;                                           // 64 f
static constexpr size_t OFF_H     = alignup(OFF_SCAL + 64*4);                    // MTOT i
static constexpr size_t OFF_PART  = alignup(OFF_H    + (size_t)MTOT*4);
static constexpr size_t OFF_PPREF = alignup(OFF_PART + (size_t)MC*4);
static constexpr size_t OFF_BST   = alignup(OFF_PPREF+ (size_t)MC*4);            // NBK+1
static constexpr size_t OFF_OFFS  = alignup(OFF_BST  + (size_t)(NBK+1)*4);       // N+1
static constexpr size_t OFF_BPACK = alignup(OFF_OFFS + (size_t)(N_NODES+1)*4);   // E2 int2
static constexpr size_t OFF_CSRC  = alignup(OFF_BPACK+ (size_t)E2*8);            // E2 i
static constexpr size_t OFF_CEA   = alignup(OFF_CSRC + (size_t)E2*4);            // E2 f
static constexpr size_t OFF_AS1P  = alignup(OFF_CEA  + (size_t)E2*4);            // N*8 f
static constexpr size_t OFF_AD1P  = alignup(OFF_AS1P + (size_t)N_NODES*8*4);
static constexpr size_t OFF_IDEN1 = alignup(OFF_AD1P + (size_t)N_NODES*8*4);
static constexpr size_t OFF_G16   = alignup(OFF_IDEN1+ (size_t)N_NODES*8*4);     // N*16 half (32B)
static constexpr size_t OFF_AD2P  = alignup(OFF_G16  + (size_t)N_NODES*16*2);    // N*8 f
static constexpr size_t OFF_H1H   = alignup(OFF_AD2P + (size_t)N_NODES*8*4);     // N*160 half
static constexpr size_t OFF_ALPH  = alignup(OFF_H1H  + (size_t)N_NODES*F1*2);    // 5*E2 f

// ---- pass 1: LDS coarse histogram + ea sum ----
__global__ __launch_bounds__(256) void k_hist(const int* __restrict__ dst, const float* __restrict__ ea,
                       int* __restrict__ H, float* __restrict__ scal){
  __shared__ int hist[NBK];
  for (int k = threadIdx.x; k < NBK; k += 256) hist[k] = 0;
  __syncthreads();
  int b = blockIdx.x;
  int e0 = b*CH, e1 = min(e0 + CH, E2);
  float s = 0.f;
  for (int e = e0 + threadIdx.x; e < e1; e += 256){
    int d;
    if (e < N_EDGES){ d = dst[e]; s += ea[e]; }
    else d = e - N_EDGES;
    atomicAdd(&hist[d >> 7], 1);
  }
  __syncthreads();
  for (int k = threadIdx.x; k < NBK; k += 256) H[(size_t)k*NBL + b] = hist[k];
  #pragma unroll
  for (int m = 1; m < 64; m <<= 1) s += __shfl_xor(s, m, 64);
  if ((threadIdx.x & 63) == 0) atomicAdd(scal, s);
}

// scal[0]=sum_ea, scal[1]=mean_ea, scal[2..6]=wedot1[h], scal[7..11]=wedot2[h]
__global__ void k_prep(const float* __restrict__ We1, const float* __restrict__ ae1,
                       const float* __restrict__ We2, const float* __restrict__ ae2,
                       float* __restrict__ scal){
  int t = threadIdx.x;
  if (t == 0) scal[1] = scal[0] / (float)N_EDGES;
  if (t < HEADS){
    float s = 0.f;
    for (int c = 0; c < C1; c++) s += We1[t*C1 + c] * ae1[t*C1 + c];
    scal[2 + t] = s;
    scal[7 + t] = We2[t] * ae2[t];
  }
}

// ---- scan of H ----
__global__ void k_s1(const int* __restrict__ H, int* __restrict__ partial){
  int i = blockIdx.x*256 + threadIdx.x;
  int v = (i < MTOT) ? H[i] : 0;
  #pragma unroll
  for (int m = 1; m < 64; m <<= 1) v += __shfl_xor(v, m, 64);
  __shared__ int sh[4];
  if ((threadIdx.x & 63) == 0) sh[threadIdx.x >> 6] = v;
  __syncthreads();
  if (threadIdx.x == 0) partial[blockIdx.x] = sh[0] + sh[1] + sh[2] + sh[3];
}

__global__ __launch_bounds__(1024) void k_s2(const int* __restrict__ partial, int* __restrict__ ppref,
                      int* __restrict__ offs, int* __restrict__ bstart){
  __shared__ int sp[1024];
  int t = threadIdx.x;
  int v = (t < MC) ? partial[t] : 0;
  sp[t] = v;
  __syncthreads();
  for (int off = 1; off < 1024; off <<= 1){
    int u = (t >= off) ? sp[t - off] : 0;
    __syncthreads();
    sp[t] += u;
    __syncthreads();
  }
  if (t < MC) ppref[t] = sp[t] - v;
  if (t == 0){ offs[N_NODES] = E2; bstart[NBK] = E2; }
}

__global__ void k_s3(int* __restrict__ H, const int* __restrict__ ppref, int* __restrict__ bstart){
  __shared__ int sp[256];
  int b = blockIdx.x, t = threadIdx.x;
  int i = b*256 + t;
  int v = (i < MTOT) ? H[i] : 0;
  sp[t] = v;
  __syncthreads();
  for (int off = 1; off < 256; off <<= 1){
    int u = (t >= off) ? sp[t - off] : 0;
    __syncthreads();
    sp[t] += u;
    __syncthreads();
  }
  int P = ppref[b] + sp[t] - v;
  if (i < MTOT){
    H[i] = P;
    if (i % NBL == 0) bstart[i / NBL] = P;
  }
}

// ---- pass 2: scatter into bucket-major packed records (8B/edge) ----
__global__ __launch_bounds__(256) void k_scat(const int* __restrict__ src, const int* __restrict__ dst,
                       const float* __restrict__ ea, const float* __restrict__ scal,
                       const int* __restrict__ H, int2* __restrict__ bpack){
  __shared__ int lofs[NBK];
  int b = blockIdx.x;
  for (int k = threadIdx.x; k < NBK; k += 256) lofs[k] = H[(size_t)k*NBL + b];
  __syncthreads();
  float mean = scal[1];
  int e0 = b*CH, e1 = min(e0 + CH, E2);
  for (int e = e0 + threadIdx.x; e < e1; e += 256){
    int d, s; float a;
    if (e < N_EDGES){ d = dst[e]; s = src[e]; a = ea[e]; }
    else { d = s = e - N_EDGES; a = mean; }
    int pos = atomicAdd(&lofs[d >> 7], 1);
    bpack[pos] = make_int2(s | ((d & 127) << 16), __float_as_int(a));
  }
}

// ---- layer 1: h1h(fp16) = x@W1, as1p/ad1p (padded 8) ----
__global__ __launch_bounds__(320) void k_h1(const float* __restrict__ x, const float* __restrict__ W1,
                    const float* __restrict__ as1w, const float* __restrict__ ad1w,
                    __half* __restrict__ h1h, float* __restrict__ as1p, float* __restrict__ ad1p){
  __shared__ float sW[5*F1];
  for (int k = threadIdx.x; k < 5*F1; k += 320) sW[k] = W1[k];
  __syncthreads();
  int nl = threadIdx.x / 80;
  int c  = threadIdx.x - nl*80;
  int n  = blockIdx.x*4 + nl;
  int c0 = 2*c;
  float hv0 = 0.f, hv1 = 0.f;
  #pragma unroll
  for (int f = 0; f < 5; f++){
    float xv = x[n*5 + f];
    hv0 += xv * sW[f*F1 + c0];
    hv1 += xv * sW[f*F1 + c0 + 1];
  }
  ((__half2*)h1h)[n*80 + c] = __floats2half2_rn(hv0, hv1);
  float vs = hv0*as1w[c0] + hv1*as1w[c0+1];
  float vd = hv0*ad1w[c0] + hv1*ad1w[c0+1];
  #pragma unroll
  for (int m = 8; m >= 1; m >>= 1){
    vs += __shfl_xor(vs, m, 64);
    vd += __shfl_xor(vd, m, 64);
  }
  if ((c & 15) == 0){
    int h = c >> 4;
    as1p[n*8 + h] = vs;
    ad1p[n*8 + h] = vd;
  }
}

// ---- pass 3: per-bucket fine sort FUSED with layer-1 softmax stats ----
__global__ __launch_bounds__(256) void k_final2(const int* __restrict__ bstart,
                        const int2* __restrict__ bpack,
                        const float* __restrict__ as1p, const float* __restrict__ ad1p,
                        const float* __restrict__ scal,
                        int* __restrict__ offs, int* __restrict__ csrc, float* __restrict__ cea,
                        float* __restrict__ alpha, float* __restrict__ iden1){
  __shared__ int cnt[128], cur[128];
  __shared__ float denL[128*HEADS];   // 2.5 KB
  __shared__ float adL [128*HEADS];
  int k = blockIdx.x, t = threadIdx.x;
  int base = k*128;
  if (t < 128) cnt[t] = 0;
  for (int i = t; i < 128*HEADS; i += 256){
    int node = base + i/HEADS;
    adL[i] = (node < N_NODES) ? ad1p[node*8 + i%HEADS] : 0.f;
    denL[i] = 0.f;
  }
  __syncthreads();
  int r0 = bstart[k], r1 = bstart[k + 1];
  for (int j = r0 + t; j < r1; j += 256) atomicAdd(&cnt[(bpack[j].x >> 16) & 127], 1);
  __syncthreads();
  if (t == 0){
    int run = 0;
    for (int i = 0; i < 128; i++){ int c = cnt[i]; cnt[i] = run; cur[i] = run; run += c; }
  }
  __syncthreads();
  if (t < 128){
    int n = base + t;
    if (n < N_NODES) offs[n] = r0 + cnt[t];
  }
  float wd[HEADS];
  #pragma unroll
  for (int h = 0; h < HEADS; h++) wd[h] = scal[2 + h];
  for (int j = r0 + t; j < r1; j += 256){
    int2 v = bpack[j];
    int s = v.x & 0xFFFF, loc = (v.x >> 16) & 127;
    float ea = __int_as_float(v.y);
    int pos = r0 + atomicAdd(&cur[loc], 1);
    csrc[pos] = s;
    cea[pos]  = ea;
    float4 g4 = *(const float4*)(as1p + s*8);
    float g5 = as1p[s*8 + 4];
    float g[HEADS] = {g4.x, g4.y, g4.z, g4.w, g5};
    #pragma unroll
    for (int h = 0; h < HEADS; h++){
      float lg = g[h] + adL[loc*HEADS + h] + ea*wd[h];
      lg = fmaxf(lg, 0.2f*lg);
      lg = fminf(lg, 50.f);
      float p = __expf(lg);
      alpha[(size_t)h*E2 + pos] = p;
      atomicAdd(&denL[loc*HEADS + h], p);
    }
  }
  __syncthreads();
  for (int i = t; i < 128*HEADS; i += 256){
    int node = base + i/HEADS;
    if (node < N_NODES) iden1[node*8 + i%HEADS] = 1.f/(denL[i] + 1e-16f);
  }
}

// ---- layer-1 aggregate (unroll 8) + relu + FUSED h2/G16/ad2p epilogue ----
__global__ __launch_bounds__(320) void k_agg1f(const int* __restrict__ offs, const int* __restrict__ csrc,
                      const float* __restrict__ alpha, const float* __restrict__ iden1,
                      const __half* __restrict__ h1h, const float* __restrict__ b1,
                      const float* __restrict__ W2, const float* __restrict__ asw2,
                      const float* __restrict__ adw2,
                      __half* __restrict__ G16, float* __restrict__ ad2p){
  __shared__ float sW2[F1*HEADS];   // 3.2 KB
  __shared__ float gacc[4*HEADS];
  int t = threadIdx.x;
  for (int i = t; i < F1*HEADS; i += 320) sW2[i] = W2[i];
  if (t < 4*HEADS) gacc[t] = 0.f;
  __syncthreads();
  int nl = t / 80;
  int c  = t - nl*80;
  int n  = blockIdx.x*4 + nl;
  int h  = c >> 4;
  const float* aph = alpha + (size_t)h*E2;
  const __half2* h12 = (const __half2*)h1h;
  int j0 = offs[n], j1 = offs[n + 1];
  float acc0 = 0.f, acc1 = 0.f;
  int j = j0;
  int jal = min(j1, (j0 + 3) & ~3);
  for (; j < jal; ++j){
    int s = csrc[j];
    float a = aph[j];
    float2 f = __half22float2(h12[(size_t)s*80 + c]);
    acc0 += a*f.x; acc1 += a*f.y;
  }
  for (; j + 7 < j1; j += 8){
    int4   sa = *(const int4*)(csrc + j);
    int4   sb = *(const int4*)(csrc + j + 4);
    float4 aa = *(const float4*)(aph + j);
    float4 ab = *(const float4*)(aph + j + 4);
    float2 f0 = __half22float2(h12[(size_t)sa.x*80 + c]);
    float2 f1 = __half22float2(h12[(size_t)sa.y*80 + c]);
    float2 f2 = __half22float2(h12[(size_t)sa.z*80 + c]);
    float2 f3 = __half22float2(h12[(size_t)sa.w*80 + c]);
    float2 f4 = __half22float2(h12[(size_t)sb.x*80 + c]);
    float2 f5 = __half22float2(h12[(size_t)sb.y*80 + c]);
    float2 f6 = __half22float2(h12[(size_t)sb.z*80 + c]);
    float2 f7 = __half22float2(h12[(size_t)sb.w*80 + c]);
    acc0 += aa.x*f0.x; acc1 += aa.x*f0.y;
    acc0 += aa.y*f1.x; acc1 += aa.y*f1.y;
    acc0 += aa.z*f2.x; acc1 += aa.z*f2.y;
    acc0 += aa.w*f3.x; acc1 += aa.w*f3.y;
    acc0 += ab.x*f4.x; acc1 += ab.x*f4.y;
    acc0 += ab.y*f5.x; acc1 += ab.y*f5.y;
    acc0 += ab.z*f6.x; acc1 += ab.z*f6.y;
    acc0 += ab.w*f7.x; acc1 += ab.w*f7.y;
  }
  for (; j + 3 < j1; j += 4){
    int4   ss = *(const int4*)(csrc + j);
    float4 aa = *(const float4*)(aph + j);
    float2 f0 = __half22float2(h12[(size_t)ss.x*80 + c]);
    float2 f1 = __half22float2(h12[(size_t)ss.y*80 + c]);
    float2 f2 = __half22float2(h12[(size_t)ss.z*80 + c]);
    float2 f3 = __half22float2(h12[(size_t)ss.w*80 + c]);
    acc0 += aa.x*f0.x; acc1 += aa.x*f0.y;
    acc0 += aa.y*f1.x; acc1 += aa.y*f1.y;
    acc0 += aa.z*f2.x; acc1 += aa.z*f2.y;
    acc0 += aa.w*f3.x; acc1 += aa.w*f3.y;
  }
  for (; j < j1; ++j){
    int s = csrc[j];
    float a = aph[j];
    float2 f = __half22float2(h12[(size_t)s*80 + c]);
    acc0 += a*f.x; acc1 += a*f.y;
  }
  float inv = iden1[n*8 + h];
  float v0 = fmaxf(acc0*inv + b1[2*c],     0.f);
  float v1 = fmaxf(acc1*inv + b1[2*c + 1], 0.f);
  // h2 partial: x2[2c]*W2[2c][:] + x2[2c+1]*W2[2c+1][:]
  #pragma unroll
  for (int hh = 0; hh < HEADS; hh++){
    float part = v0*sW2[(2*c)*HEADS + hh] + v1*sW2[(2*c + 1)*HEADS + hh];
    atomicAdd(&gacc[nl*HEADS + hh], part);
  }
  __syncthreads();
  if (c == 0){
    #pragma unroll
    for (int hh = 0; hh < HEADS; hh++){
      float h2v = gacc[nl*HEADS + hh];
      G16[(size_t)n*16 + hh]     = __float2half(h2v);
      G16[(size_t)n*16 + 5 + hh] = __float2half(h2v * asw2[hh]);
      ad2p[n*8 + hh]             = h2v * adw2[hh];
    }
    #pragma unroll
    for (int z = 10; z < 16; z++) G16[(size_t)n*16 + z] = __float2half(0.f);
  }
}

// ---- layer 2: wave-per-node single-sweep softmax aggregate + mean + linear + sigmoid ----
__global__ __launch_bounds__(256) void k_agg2(const int* __restrict__ offs, const int* __restrict__ csrc,
                      const float* __restrict__ cea,
                      const __half* __restrict__ G16, const float* __restrict__ ad2p,
                      const float* __restrict__ scal,
                      const float* __restrict__ b2, const float* __restrict__ Wlin,
                      float* __restrict__ out){
  int w = threadIdx.x >> 6, l = threadIdx.x & 63;
  int n = blockIdx.x*4 + w;
  float adn[HEADS], wd[HEADS];
  #pragma unroll
  for (int h = 0; h < HEADS; h++){ adn[h] = ad2p[n*8 + h]; wd[h] = scal[7 + h]; }
  int j0 = offs[n], j1 = offs[n + 1];

  float den[HEADS] = {0,0,0,0,0};
  float ac[HEADS]  = {0,0,0,0,0};
  for (int j = j0 + l; j < j1; j += 64){
    int s = csrc[j];
    float c = cea[j];
    const __half* gs = G16 + (size_t)s*16;
    union { uint4 u; __half2 h[4]; } U; U.u = *(const uint4*)gs;
    union { uint2 u; __half2 h[2]; } V; V.u = *(const uint2*)(gs + 8);
    float2 p01 = __half22float2(U.h[0]);   // h2_0, h2_1
    float2 p23 = __half22float2(U.h[1]);   // h2_2, h2_3
    float2 p45 = __half22float2(U.h[2]);   // h2_4, as2_0
    float2 p67 = __half22float2(U.h[3]);   // as2_1, as2_2
    float2 p89 = __half22float2(V.h[0]);   // as2_3, as2_4
    float hv[HEADS] = {p01.x, p01.y, p23.x, p23.y, p45.x};
    float av[HEADS] = {p45.y, p67.x, p67.y, p89.x, p89.y};
    #pragma unroll
    for (int h = 0; h < HEADS; h++){
      float lg = av[h] + adn[h] + c*wd[h];
      lg = fmaxf(lg, 0.2f*lg);
      lg = fminf(lg, 50.f);
      float p = __expf(lg);
      den[h] += p;
      ac[h]  += p * hv[h];
    }
  }
  #pragma unroll
  for (int m = 1; m < 64; m <<= 1){
    #pragma unroll
    for (int h = 0; h < HEADS; h++){
      den[h] += __shfl_xor(den[h], m, 64);
      ac[h]  += __shfl_xor(ac[h], m, 64);
    }
  }
  if (l == 0){
    float v = 0.f;
    #pragma unroll
    for (int h = 0; h < HEADS; h++) v += ac[h] / (den[h] + 1e-16f);
    v = v * (1.f/HEADS) + b2[0];
    v *= Wlin[0];
    out[n] = 1.f / (1.f + __expf(-v));
  }
}

extern "C" void kernel_launch(void* const* d_in, const int* in_sizes, int n_in,
                              void* d_out, int out_size, void* d_ws, size_t ws_size,
                              hipStream_t stream) {
  const float* x    = (const float*)d_in[0];
  const float* ea   = (const float*)d_in[1];
  const int*   src  = (const int*)d_in[2];
  const int*   dst  = (const int*)d_in[3];
  const float* W1   = (const float*)d_in[4];
  const float* as1w = (const float*)d_in[5];
  const float* ad1w = (const float*)d_in[6];
  const float* We1  = (const float*)d_in[7];
  const float* ae1  = (const float*)d_in[8];
  const float* b1   = (const float*)d_in[9];
  const float* W2   = (const float*)d_in[10];
  const float* as2w = (const float*)d_in[11];
  const float* ad2w = (const float*)d_in[12];
  const float* We2  = (const float*)d_in[13];
  const float* ae2  = (const float*)d_in[14];
  const float* b2   = (const float*)d_in[15];
  const float* Wlin = (const float*)d_in[16];

  char* ws = (char*)d_ws;
  float* scal   = (float*)(ws + OFF_SCAL);
  int*   H      = (int*)  (ws + OFF_H);
  int*   part   = (int*)  (ws + OFF_PART);
  int*   ppref  = (int*)  (ws + OFF_PPREF);
  int*   bstart = (int*)  (ws + OFF_BST);
  int*   offs   = (int*)  (ws + OFF_OFFS);
  int2*  bpack  = (int2*) (ws + OFF_BPACK);
  int*   csrc   = (int*)  (ws + OFF_CSRC);
  float* cea    = (float*)(ws + OFF_CEA);
  float* as1p   = (float*)(ws + OFF_AS1P);
  float* ad1p   = (float*)(ws + OFF_AD1P);
  float* iden1  = (float*)(ws + OFF_IDEN1);
  __half* G16   = (__half*)(ws + OFF_G16);
  float* ad2p   = (float*)(ws + OFF_AD2P);
  __half* h1h   = (__half*)(ws + OFF_H1H);
  float* alpha  = (float*)(ws + OFF_ALPH);
  float* outp   = (float*)d_out;

  hipMemsetAsync(scal, 0, 64*sizeof(float), stream);

  k_h1     <<<N_NODES/4, 320, 0, stream>>>(x, W1, as1w, ad1w, h1h, as1p, ad1p);
  k_hist   <<<NBL, 256, 0, stream>>>(dst, ea, H, scal);
  k_prep   <<<1, 64, 0, stream>>>(We1, ae1, We2, ae2, scal);
  k_s1     <<<MC, 256, 0, stream>>>(H, part);
  k_s2     <<<1, 1024, 0, stream>>>(part, ppref, offs, bstart);
  k_s3     <<<MC, 256, 0, stream>>>(H, ppref, bstart);
  k_scat   <<<NBL, 256, 0, stream>>>(src, dst, ea, scal, H, bpack);
  k_final2 <<<NBK, 256, 0, stream>>>(bstart, bpack, as1p, ad1p, scal, offs, csrc, cea, alpha, iden1);

  k_agg1f  <<<N_NODES/4, 320, 0, stream>>>(offs, csrc, alpha, iden1, h1h, b1, W2, as2w, ad2w, G16, ad2p);
  k_agg2   <<<N_NODES/4, 256, 0, stream>>>(offs, csrc, cea, G16, ad2p, scal, b2, Wlin, outp);
}

// Round 9
// 324.035 us; speedup vs baseline: 3.6356x; 1.2770x over previous
//
#include <hip/hip_runtime.h>
#include <hip/hip_fp16.h>
#include <math.h>

#define N_NODES 50000
#define N_EDGES 800000
#define E2 (N_EDGES + N_NODES)   // 850000
#define HEADS 5
#define C1 32
#define F1 160

// counting-sort CSR build (128-node buckets)
#define NBK 391
#define NBL 416
#define CH  2044                 // 416*2044 >= E2
#define MTOT (NBK*NBL)           // 162656
#define MC  636                  // ceil(MTOT/256)

static constexpr size_t alignup(size_t x){ return (x + 255) & ~size_t(255); }
static constexpr size_t OFF_SCAL  = 0;                                           // 64 f
static constexpr size_t OFF_H     = alignup(OFF_SCAL + 64*4);                    // MTOT i
static constexpr size_t OFF_PART  = alignup(OFF_H    + (size_t)MTOT*4);
static constexpr size_t OFF_PPREF = alignup(OFF_PART + (size_t)MC*4);
static constexpr size_t OFF_BST   = alignup(OFF_PPREF+ (size_t)MC*4);            // NBK+1
static constexpr size_t OFF_OFFS  = alignup(OFF_BST  + (size_t)(NBK+1)*4);       // N+1
static constexpr size_t OFF_BPACK = alignup(OFF_OFFS + (size_t)(N_NODES+1)*4);   // E2 int2
static constexpr size_t OFF_CSRC  = alignup(OFF_BPACK+ (size_t)E2*8);            // E2 i
static constexpr size_t OFF_CEA   = alignup(OFF_CSRC + (size_t)E2*4);            // E2 f
static constexpr size_t OFF_AS1P  = alignup(OFF_CEA  + (size_t)E2*4);            // N*8 f
static constexpr size_t OFF_AD1P  = alignup(OFF_AS1P + (size_t)N_NODES*8*4);
static constexpr size_t OFF_IDEN1 = alignup(OFF_AD1P + (size_t)N_NODES*8*4);
static constexpr size_t OFF_G16   = alignup(OFF_IDEN1+ (size_t)N_NODES*8*4);     // N*16 half
static constexpr size_t OFF_AD2P  = alignup(OFF_G16  + (size_t)N_NODES*16*2);    // N*8 f
static constexpr size_t OFF_H1H   = alignup(OFF_AD2P + (size_t)N_NODES*8*4);     // N*160 half
static constexpr size_t OFF_X2H   = alignup(OFF_H1H  + (size_t)N_NODES*F1*2);    // N*160 half
static constexpr size_t OFF_ALPH  = alignup(OFF_X2H  + (size_t)N_NODES*F1*2);    // 5*E2 f

// ---- pass 1: LDS coarse histogram + ea sum ----
__global__ __launch_bounds__(256) void k_hist(const int* __restrict__ dst, const float* __restrict__ ea,
                       int* __restrict__ H, float* __restrict__ scal){
  __shared__ int hist[NBK];
  for (int k = threadIdx.x; k < NBK; k += 256) hist[k] = 0;
  __syncthreads();
  int b = blockIdx.x;
  int e0 = b*CH, e1 = min(e0 + CH, E2);
  float s = 0.f;
  for (int e = e0 + threadIdx.x; e < e1; e += 256){
    int d;
    if (e < N_EDGES){ d = dst[e]; s += ea[e]; }
    else d = e - N_EDGES;
    atomicAdd(&hist[d >> 7], 1);
  }
  __syncthreads();
  for (int k = threadIdx.x; k < NBK; k += 256) H[(size_t)k*NBL + b] = hist[k];
  #pragma unroll
  for (int m = 1; m < 64; m <<= 1) s += __shfl_xor(s, m, 64);
  if ((threadIdx.x & 63) == 0) atomicAdd(scal, s);
}

// scal[0]=sum_ea, scal[1]=mean_ea, scal[2..6]=wedot1[h], scal[7..11]=wedot2[h]
__global__ void k_prep(const float* __restrict__ We1, const float* __restrict__ ae1,
                       const float* __restrict__ We2, const float* __restrict__ ae2,
                       float* __restrict__ scal){
  int t = threadIdx.x;
  if (t == 0) scal[1] = scal[0] / (float)N_EDGES;
  if (t < HEADS){
    float s = 0.f;
    for (int c = 0; c < C1; c++) s += We1[t*C1 + c] * ae1[t*C1 + c];
    scal[2 + t] = s;
    scal[7 + t] = We2[t] * ae2[t];
  }
}

// ---- scan of H ----
__global__ void k_s1(const int* __restrict__ H, int* __restrict__ partial){
  int i = blockIdx.x*256 + threadIdx.x;
  int v = (i < MTOT) ? H[i] : 0;
  #pragma unroll
  for (int m = 1; m < 64; m <<= 1) v += __shfl_xor(v, m, 64);
  __shared__ int sh[4];
  if ((threadIdx.x & 63) == 0) sh[threadIdx.x >> 6] = v;
  __syncthreads();
  if (threadIdx.x == 0) partial[blockIdx.x] = sh[0] + sh[1] + sh[2] + sh[3];
}

__global__ __launch_bounds__(1024) void k_s2(const int* __restrict__ partial, int* __restrict__ ppref,
                      int* __restrict__ offs, int* __restrict__ bstart){
  __shared__ int sp[1024];
  int t = threadIdx.x;
  int v = (t < MC) ? partial[t] : 0;
  sp[t] = v;
  __syncthreads();
  for (int off = 1; off < 1024; off <<= 1){
    int u = (t >= off) ? sp[t - off] : 0;
    __syncthreads();
    sp[t] += u;
    __syncthreads();
  }
  if (t < MC) ppref[t] = sp[t] - v;
  if (t == 0){ offs[N_NODES] = E2; bstart[NBK] = E2; }
}

__global__ void k_s3(int* __restrict__ H, const int* __restrict__ ppref, int* __restrict__ bstart){
  __shared__ int sp[256];
  int b = blockIdx.x, t = threadIdx.x;
  int i = b*256 + t;
  int v = (i < MTOT) ? H[i] : 0;
  sp[t] = v;
  __syncthreads();
  for (int off = 1; off < 256; off <<= 1){
    int u = (t >= off) ? sp[t - off] : 0;
    __syncthreads();
    sp[t] += u;
    __syncthreads();
  }
  int P = ppref[b] + sp[t] - v;
  if (i < MTOT){
    H[i] = P;
    if (i % NBL == 0) bstart[i / NBL] = P;
  }
}

// ---- pass 2: scatter into bucket-major packed records (8B/edge) ----
__global__ __launch_bounds__(256) void k_scat(const int* __restrict__ src, const int* __restrict__ dst,
                       const float* __restrict__ ea, const float* __restrict__ scal,
                       const int* __restrict__ H, int2* __restrict__ bpack){
  __shared__ int lofs[NBK];
  int b = blockIdx.x;
  for (int k = threadIdx.x; k < NBK; k += 256) lofs[k] = H[(size_t)k*NBL + b];
  __syncthreads();
  float mean = scal[1];
  int e0 = b*CH, e1 = min(e0 + CH, E2);
  for (int e = e0 + threadIdx.x; e < e1; e += 256){
    int d, s; float a;
    if (e < N_EDGES){ d = dst[e]; s = src[e]; a = ea[e]; }
    else { d = s = e - N_EDGES; a = mean; }
    int pos = atomicAdd(&lofs[d >> 7], 1);
    bpack[pos] = make_int2(s | ((d & 127) << 16), __float_as_int(a));
  }
}

// ---- layer 1: h1h(fp16) = x@W1, as1p/ad1p (padded 8) ----
__global__ __launch_bounds__(320) void k_h1(const float* __restrict__ x, const float* __restrict__ W1,
                    const float* __restrict__ as1w, const float* __restrict__ ad1w,
                    __half* __restrict__ h1h, float* __restrict__ as1p, float* __restrict__ ad1p){
  __shared__ float sW[5*F1];
  for (int k = threadIdx.x; k < 5*F1; k += 320) sW[k] = W1[k];
  __syncthreads();
  int nl = threadIdx.x / 80;
  int c  = threadIdx.x - nl*80;
  int n  = blockIdx.x*4 + nl;
  int c0 = 2*c;
  float hv0 = 0.f, hv1 = 0.f;
  #pragma unroll
  for (int f = 0; f < 5; f++){
    float xv = x[n*5 + f];
    hv0 += xv * sW[f*F1 + c0];
    hv1 += xv * sW[f*F1 + c0 + 1];
  }
  ((__half2*)h1h)[n*80 + c] = __floats2half2_rn(hv0, hv1);
  float vs = hv0*as1w[c0] + hv1*as1w[c0+1];
  float vd = hv0*ad1w[c0] + hv1*ad1w[c0+1];
  #pragma unroll
  for (int m = 8; m >= 1; m >>= 1){
    vs += __shfl_xor(vs, m, 64);
    vd += __shfl_xor(vd, m, 64);
  }
  if ((c & 15) == 0){
    int h = c >> 4;
    as1p[n*8 + h] = vs;
    ad1p[n*8 + h] = vd;
  }
}

// ---- pass 3: per-bucket fine sort FUSED with layer-1 softmax stats ----
__global__ __launch_bounds__(256) void k_final2(const int* __restrict__ bstart,
                        const int2* __restrict__ bpack,
                        const float* __restrict__ as1p, const float* __restrict__ ad1p,
                        const float* __restrict__ scal,
                        int* __restrict__ offs, int* __restrict__ csrc, float* __restrict__ cea,
                        float* __restrict__ alpha, float* __restrict__ iden1){
  __shared__ int cnt[128], cur[128];
  __shared__ float denL[128*HEADS];
  __shared__ float adL [128*HEADS];
  int k = blockIdx.x, t = threadIdx.x;
  int base = k*128;
  if (t < 128) cnt[t] = 0;
  for (int i = t; i < 128*HEADS; i += 256){
    int node = base + i/HEADS;
    adL[i] = (node < N_NODES) ? ad1p[node*8 + i%HEADS] : 0.f;
    denL[i] = 0.f;
  }
  __syncthreads();
  int r0 = bstart[k], r1 = bstart[k + 1];
  for (int j = r0 + t; j < r1; j += 256) atomicAdd(&cnt[(bpack[j].x >> 16) & 127], 1);
  __syncthreads();
  if (t == 0){
    int run = 0;
    for (int i = 0; i < 128; i++){ int c = cnt[i]; cnt[i] = run; cur[i] = run; run += c; }
  }
  __syncthreads();
  if (t < 128){
    int n = base + t;
    if (n < N_NODES) offs[n] = r0 + cnt[t];
  }
  float wd[HEADS];
  #pragma unroll
  for (int h = 0; h < HEADS; h++) wd[h] = scal[2 + h];
  for (int j = r0 + t; j < r1; j += 256){
    int2 v = bpack[j];
    int s = v.x & 0xFFFF, loc = (v.x >> 16) & 127;
    float ea = __int_as_float(v.y);
    int pos = r0 + atomicAdd(&cur[loc], 1);
    csrc[pos] = s;
    cea[pos]  = ea;
    float4 g4 = *(const float4*)(as1p + s*8);
    float g5 = as1p[s*8 + 4];
    float g[HEADS] = {g4.x, g4.y, g4.z, g4.w, g5};
    #pragma unroll
    for (int h = 0; h < HEADS; h++){
      float lg = g[h] + adL[loc*HEADS + h] + ea*wd[h];
      lg = fmaxf(lg, 0.2f*lg);
      lg = fminf(lg, 50.f);
      float p = __expf(lg);
      alpha[(size_t)h*E2 + pos] = p;
      atomicAdd(&denL[loc*HEADS + h], p);
    }
  }
  __syncthreads();
  for (int i = t; i < 128*HEADS; i += 256){
    int node = base + i/HEADS;
    if (node < N_NODES) iden1[node*8 + i%HEADS] = 1.f/(denL[i] + 1e-16f);
  }
}

// ---- layer 1 aggregate: pure FMA gather, unroll 8 -> x2h(fp16) (R5-proven) ----
__global__ __launch_bounds__(320) void k_agg1(const int* __restrict__ offs, const int* __restrict__ csrc,
                      const float* __restrict__ alpha, const float* __restrict__ iden1,
                      const __half* __restrict__ h1h,
                      const float* __restrict__ b1, __half* __restrict__ x2h){
  int nl = threadIdx.x / 80;
  int c  = threadIdx.x - nl*80;
  int n  = blockIdx.x*4 + nl;
  int h  = c >> 4;
  const float* aph = alpha + (size_t)h*E2;
  const __half2* h12 = (const __half2*)h1h;
  int j0 = offs[n], j1 = offs[n + 1];
  float acc0 = 0.f, acc1 = 0.f;
  int j = j0;
  int jal = min(j1, (j0 + 3) & ~3);
  for (; j < jal; ++j){
    int s = csrc[j];
    float a = aph[j];
    float2 f = __half22float2(h12[(size_t)s*80 + c]);
    acc0 += a*f.x; acc1 += a*f.y;
  }
  for (; j + 7 < j1; j += 8){
    int4   sa = *(const int4*)(csrc + j);
    int4   sb = *(const int4*)(csrc + j + 4);
    float4 aa = *(const float4*)(aph + j);
    float4 ab = *(const float4*)(aph + j + 4);
    float2 f0 = __half22float2(h12[(size_t)sa.x*80 + c]);
    float2 f1 = __half22float2(h12[(size_t)sa.y*80 + c]);
    float2 f2 = __half22float2(h12[(size_t)sa.z*80 + c]);
    float2 f3 = __half22float2(h12[(size_t)sa.w*80 + c]);
    float2 f4 = __half22float2(h12[(size_t)sb.x*80 + c]);
    float2 f5 = __half22float2(h12[(size_t)sb.y*80 + c]);
    float2 f6 = __half22float2(h12[(size_t)sb.z*80 + c]);
    float2 f7 = __half22float2(h12[(size_t)sb.w*80 + c]);
    acc0 += aa.x*f0.x; acc1 += aa.x*f0.y;
    acc0 += aa.y*f1.x; acc1 += aa.y*f1.y;
    acc0 += aa.z*f2.x; acc1 += aa.z*f2.y;
    acc0 += aa.w*f3.x; acc1 += aa.w*f3.y;
    acc0 += ab.x*f4.x; acc1 += ab.x*f4.y;
    acc0 += ab.y*f5.x; acc1 += ab.y*f5.y;
    acc0 += ab.z*f6.x; acc1 += ab.z*f6.y;
    acc0 += ab.w*f7.x; acc1 += ab.w*f7.y;
  }
  for (; j + 3 < j1; j += 4){
    int4   ss = *(const int4*)(csrc + j);
    float4 aa = *(const float4*)(aph + j);
    float2 f0 = __half22float2(h12[(size_t)ss.x*80 + c]);
    float2 f1 = __half22float2(h12[(size_t)ss.y*80 + c]);
    float2 f2 = __half22float2(h12[(size_t)ss.z*80 + c]);
    float2 f3 = __half22float2(h12[(size_t)ss.w*80 + c]);
    acc0 += aa.x*f0.x; acc1 += aa.x*f0.y;
    acc0 += aa.y*f1.x; acc1 += aa.y*f1.y;
    acc0 += aa.z*f2.x; acc1 += aa.z*f2.y;
    acc0 += aa.w*f3.x; acc1 += aa.w*f3.y;
  }
  for (; j < j1; ++j){
    int s = csrc[j];
    float a = aph[j];
    float2 f = __half22float2(h12[(size_t)s*80 + c]);
    acc0 += a*f.x; acc1 += a*f.y;
  }
  float inv = iden1[n*8 + h];
  float v0 = fmaxf(acc0*inv + b1[2*c],     0.f);
  float v1 = fmaxf(acc1*inv + b1[2*c + 1], 0.f);
  ((__half2*)x2h)[(size_t)n*80 + c] = __floats2half2_rn(v0, v1);
}

// ---- layer 2: h2 = x2h@W2 -> packed fp16 G16 ([0..4]=h2, [5..9]=as2) + ad2p ----
__global__ __launch_bounds__(256) void k_h2(const __half* __restrict__ x2h, const float* __restrict__ W2,
                    const float* __restrict__ asw2, const float* __restrict__ adw2,
                    __half* __restrict__ G16, float* __restrict__ ad2p){
  __shared__ float sW[F1*HEADS];
  for (int k = threadIdx.x; k < F1*HEADS; k += 256) sW[k] = W2[k];
  __syncthreads();
  int w = threadIdx.x >> 6, l = threadIdx.x & 63;
  int n = blockIdx.x*4 + w;
  const __half2* x22 = (const __half2*)x2h;
  float acc[HEADS] = {0.f, 0.f, 0.f, 0.f, 0.f};
  for (int k2 = l; k2 < 80; k2 += 64){
    float2 f = __half22float2(x22[(size_t)n*80 + k2]);
    #pragma unroll
    for (int h = 0; h < HEADS; h++)
      acc[h] += f.x * sW[(2*k2)*HEADS + h] + f.y * sW[(2*k2+1)*HEADS + h];
  }
  #pragma unroll
  for (int m = 1; m < 64; m <<= 1){
    #pragma unroll
    for (int h = 0; h < HEADS; h++) acc[h] += __shfl_xor(acc[h], m, 64);
  }
  if (l == 0){
    #pragma unroll
    for (int h = 0; h < HEADS; h++){
      G16[(size_t)n*16 + h]     = __float2half(acc[h]);
      G16[(size_t)n*16 + 5 + h] = __float2half(acc[h] * asw2[h]);
      ad2p[n*8 + h]             = acc[h] * adw2[h];
    }
    #pragma unroll
    for (int z = 10; z < 16; z++) G16[(size_t)n*16 + z] = __float2half(0.f);
  }
}

// ---- layer 2: wave-per-node single-sweep softmax aggregate + mean + linear + sigmoid ----
__global__ __launch_bounds__(256) void k_agg2(const int* __restrict__ offs, const int* __restrict__ csrc,
                      const float* __restrict__ cea,
                      const __half* __restrict__ G16, const float* __restrict__ ad2p,
                      const float* __restrict__ scal,
                      const float* __restrict__ b2, const float* __restrict__ Wlin,
                      float* __restrict__ out){
  int w = threadIdx.x >> 6, l = threadIdx.x & 63;
  int n = blockIdx.x*4 + w;
  float adn[HEADS], wd[HEADS];
  #pragma unroll
  for (int h = 0; h < HEADS; h++){ adn[h] = ad2p[n*8 + h]; wd[h] = scal[7 + h]; }
  int j0 = offs[n], j1 = offs[n + 1];

  float den[HEADS] = {0,0,0,0,0};
  float ac[HEADS]  = {0,0,0,0,0};
  for (int j = j0 + l; j < j1; j += 64){
    int s = csrc[j];
    float c = cea[j];
    const __half* gs = G16 + (size_t)s*16;
    union { uint4 u; __half2 h[4]; } U; U.u = *(const uint4*)gs;
    union { uint2 u; __half2 h[2]; } V; V.u = *(const uint2*)(gs + 8);
    float2 p01 = __half22float2(U.h[0]);
    float2 p23 = __half22float2(U.h[1]);
    float2 p45 = __half22float2(U.h[2]);
    float2 p67 = __half22float2(U.h[3]);
    float2 p89 = __half22float2(V.h[0]);
    float hv[HEADS] = {p01.x, p01.y, p23.x, p23.y, p45.x};
    float av[HEADS] = {p45.y, p67.x, p67.y, p89.x, p89.y};
    #pragma unroll
    for (int h = 0; h < HEADS; h++){
      float lg = av[h] + adn[h] + c*wd[h];
      lg = fmaxf(lg, 0.2f*lg);
      lg = fminf(lg, 50.f);
      float p = __expf(lg);
      den[h] += p;
      ac[h]  += p * hv[h];
    }
  }
  #pragma unroll
  for (int m = 1; m < 64; m <<= 1){
    #pragma unroll
    for (int h = 0; h < HEADS; h++){
      den[h] += __shfl_xor(den[h], m, 64);
      ac[h]  += __shfl_xor(ac[h], m, 64);
    }
  }
  if (l == 0){
    float v = 0.f;
    #pragma unroll
    for (int h = 0; h < HEADS; h++) v += ac[h] / (den[h] + 1e-16f);
    v = v * (1.f/HEADS) + b2[0];
    v *= Wlin[0];
    out[n] = 1.f / (1.f + __expf(-v));
  }
}

extern "C" void kernel_launch(void* const* d_in, const int* in_sizes, int n_in,
                              void* d_out, int out_size, void* d_ws, size_t ws_size,
                              hipStream_t stream) {
  const float* x    = (const float*)d_in[0];
  const float* ea   = (const float*)d_in[1];
  const int*   src  = (const int*)d_in[2];
  const int*   dst  = (const int*)d_in[3];
  const float* W1   = (const float*)d_in[4];
  const float* as1w = (const float*)d_in[5];
  const float* ad1w = (const float*)d_in[6];
  const float* We1  = (const float*)d_in[7];
  const float* ae1  = (const float*)d_in[8];
  const float* b1   = (const float*)d_in[9];
  const float* W2   = (const float*)d_in[10];
  const float* as2w = (const float*)d_in[11];
  const float* ad2w = (const float*)d_in[12];
  const float* We2  = (const float*)d_in[13];
  const float* ae2  = (const float*)d_in[14];
  const float* b2   = (const float*)d_in[15];
  const float* Wlin = (const float*)d_in[16];

  char* ws = (char*)d_ws;
  float* scal   = (float*)(ws + OFF_SCAL);
  int*   H      = (int*)  (ws + OFF_H);
  int*   part   = (int*)  (ws + OFF_PART);
  int*   ppref  = (int*)  (ws + OFF_PPREF);
  int*   bstart = (int*)  (ws + OFF_BST);
  int*   offs   = (int*)  (ws + OFF_OFFS);
  int2*  bpack  = (int2*) (ws + OFF_BPACK);
  int*   csrc   = (int*)  (ws + OFF_CSRC);
  float* cea    = (float*)(ws + OFF_CEA);
  float* as1p   = (float*)(ws + OFF_AS1P);
  float* ad1p   = (float*)(ws + OFF_AD1P);
  float* iden1  = (float*)(ws + OFF_IDEN1);
  __half* G16   = (__half*)(ws + OFF_G16);
  float* ad2p   = (float*)(ws + OFF_AD2P);
  __half* h1h   = (__half*)(ws + OFF_H1H);
  __half* x2h   = (__half*)(ws + OFF_X2H);
  float* alpha  = (float*)(ws + OFF_ALPH);
  float* outp   = (float*)d_out;

  hipMemsetAsync(scal, 0, 64*sizeof(float), stream);

  k_h1     <<<N_NODES/4, 320, 0, stream>>>(x, W1, as1w, ad1w, h1h, as1p, ad1p);
  k_hist   <<<NBL, 256, 0, stream>>>(dst, ea, H, scal);
  k_prep   <<<1, 64, 0, stream>>>(We1, ae1, We2, ae2, scal);
  k_s1     <<<MC, 256, 0, stream>>>(H, part);
  k_s2     <<<1, 1024, 0, stream>>>(part, ppref, offs, bstart);
  k_s3     <<<MC, 256, 0, stream>>>(H, ppref, bstart);
  k_scat   <<<NBL, 256, 0, stream>>>(src, dst, ea, scal, H, bpack);
  k_final2 <<<NBK, 256, 0, stream>>>(bstart, bpack, as1p, ad1p, scal, offs, csrc, cea, alpha, iden1);

  k_agg1   <<<N_NODES/4, 320, 0, stream>>>(offs, csrc, alpha, iden1, h1h, b1, x2h);
  k_h2     <<<N_NODES/4, 256, 0, stream>>>(x2h, W2, as2w, ad2w, G16, ad2p);
  k_agg2   <<<N_NODES/4, 256, 0, stream>>>(offs, csrc, cea, G16, ad2p, scal, b2, Wlin, outp);
}

// Round 10
// 302.479 us; speedup vs baseline: 3.8947x; 1.0713x over previous
//
#include <hip/hip_runtime.h>
#include <hip/hip_fp16.h>
#include <math.h>

#define N_NODES 50000
#define N_EDGES 800000
#define E2 (N_EDGES + N_NODES)   // 850000
#define HEADS 5
#define C1 32
#define F1 160

// counting-sort CSR build (128-node buckets)
#define NBK 391
#define NBL 128                  // fewer, longer chunks: ~17-edge runs per (bucket,block) -> low write amp
#define CH  6641                 // 128*6641 = 850048 >= E2
#define MTOT (NBK*NBL)           // 50048
#define MC  196                  // ceil(MTOT/256)

static constexpr size_t alignup(size_t x){ return (x + 255) & ~size_t(255); }
static constexpr size_t OFF_SCAL  = 0;                                           // 64 f
static constexpr size_t OFF_H     = alignup(OFF_SCAL + 64*4);                    // MTOT i
static constexpr size_t OFF_PART  = alignup(OFF_H    + (size_t)MTOT*4);
static constexpr size_t OFF_PPREF = alignup(OFF_PART + (size_t)MC*4);
static constexpr size_t OFF_BST   = alignup(OFF_PPREF+ (size_t)MC*4);            // NBK+1
static constexpr size_t OFF_OFFS  = alignup(OFF_BST  + (size_t)(NBK+1)*4);       // N+1
static constexpr size_t OFF_BPACK = alignup(OFF_OFFS + (size_t)(N_NODES+1)*4);   // E2 int2
static constexpr size_t OFF_CSRC  = alignup(OFF_BPACK+ (size_t)E2*8);            // E2 i
static constexpr size_t OFF_CEA   = alignup(OFF_CSRC + (size_t)E2*4);            // E2 f
static constexpr size_t OFF_AS1P  = alignup(OFF_CEA  + (size_t)E2*4);            // N*8 f
static constexpr size_t OFF_AD1P  = alignup(OFF_AS1P + (size_t)N_NODES*8*4);
static constexpr size_t OFF_IDEN1 = alignup(OFF_AD1P + (size_t)N_NODES*8*4);
static constexpr size_t OFF_G16   = alignup(OFF_IDEN1+ (size_t)N_NODES*8*4);     // N*16 half
static constexpr size_t OFF_AD2P  = alignup(OFF_G16  + (size_t)N_NODES*16*2);    // N*8 f
static constexpr size_t OFF_H1H   = alignup(OFF_AD2P + (size_t)N_NODES*8*4);     // N*160 half
static constexpr size_t OFF_X2H   = alignup(OFF_H1H  + (size_t)N_NODES*F1*2);    // N*160 half
static constexpr size_t OFF_ALPH  = alignup(OFF_X2H  + (size_t)N_NODES*F1*2);    // 5*E2 half

// ---- pass 1: LDS coarse histogram + ea sum ----
__global__ __launch_bounds__(256) void k_hist(const int* __restrict__ dst, const float* __restrict__ ea,
                       int* __restrict__ H, float* __restrict__ scal){
  __shared__ int hist[NBK];
  for (int k = threadIdx.x; k < NBK; k += 256) hist[k] = 0;
  __syncthreads();
  int b = blockIdx.x;
  int e0 = b*CH, e1 = min(e0 + CH, E2);
  float s = 0.f;
  for (int e = e0 + threadIdx.x; e < e1; e += 256){
    int d;
    if (e < N_EDGES){ d = dst[e]; s += ea[e]; }
    else d = e - N_EDGES;
    atomicAdd(&hist[d >> 7], 1);
  }
  __syncthreads();
  for (int k = threadIdx.x; k < NBK; k += 256) H[(size_t)k*NBL + b] = hist[k];
  #pragma unroll
  for (int m = 1; m < 64; m <<= 1) s += __shfl_xor(s, m, 64);
  if ((threadIdx.x & 63) == 0) atomicAdd(scal, s);
}

// scal[0]=sum_ea, scal[1]=mean_ea, scal[2..6]=wedot1[h], scal[7..11]=wedot2[h]
__global__ void k_prep(const float* __restrict__ We1, const float* __restrict__ ae1,
                       const float* __restrict__ We2, const float* __restrict__ ae2,
                       float* __restrict__ scal){
  int t = threadIdx.x;
  if (t == 0) scal[1] = scal[0] / (float)N_EDGES;
  if (t < HEADS){
    float s = 0.f;
    for (int c = 0; c < C1; c++) s += We1[t*C1 + c] * ae1[t*C1 + c];
    scal[2 + t] = s;
    scal[7 + t] = We2[t] * ae2[t];
  }
}

// ---- scan of H ----
__global__ void k_s1(const int* __restrict__ H, int* __restrict__ partial){
  int i = blockIdx.x*256 + threadIdx.x;
  int v = (i < MTOT) ? H[i] : 0;
  #pragma unroll
  for (int m = 1; m < 64; m <<= 1) v += __shfl_xor(v, m, 64);
  __shared__ int sh[4];
  if ((threadIdx.x & 63) == 0) sh[threadIdx.x >> 6] = v;
  __syncthreads();
  if (threadIdx.x == 0) partial[blockIdx.x] = sh[0] + sh[1] + sh[2] + sh[3];
}

__global__ __launch_bounds__(256) void k_s2(const int* __restrict__ partial, int* __restrict__ ppref,
                      int* __restrict__ offs, int* __restrict__ bstart){
  __shared__ int sp[256];
  int t = threadIdx.x;
  int v = (t < MC) ? partial[t] : 0;
  sp[t] = v;
  __syncthreads();
  for (int off = 1; off < 256; off <<= 1){
    int u = (t >= off) ? sp[t - off] : 0;
    __syncthreads();
    sp[t] += u;
    __syncthreads();
  }
  if (t < MC) ppref[t] = sp[t] - v;
  if (t == 0){ offs[N_NODES] = E2; bstart[NBK] = E2; }
}

__global__ void k_s3(int* __restrict__ H, const int* __restrict__ ppref, int* __restrict__ bstart){
  __shared__ int sp[256];
  int b = blockIdx.x, t = threadIdx.x;
  int i = b*256 + t;
  int v = (i < MTOT) ? H[i] : 0;
  sp[t] = v;
  __syncthreads();
  for (int off = 1; off < 256; off <<= 1){
    int u = (t >= off) ? sp[t - off] : 0;
    __syncthreads();
    sp[t] += u;
    __syncthreads();
  }
  int P = ppref[b] + sp[t] - v;
  if (i < MTOT){
    H[i] = P;
    if (i % NBL == 0) bstart[i / NBL] = P;
  }
}

// ---- pass 2: scatter into bucket-major packed records (8B/edge) ----
__global__ __launch_bounds__(256) void k_scat(const int* __restrict__ src, const int* __restrict__ dst,
                       const float* __restrict__ ea, const float* __restrict__ scal,
                       const int* __restrict__ H, int2* __restrict__ bpack){
  __shared__ int lofs[NBK];
  int b = blockIdx.x;
  for (int k = threadIdx.x; k < NBK; k += 256) lofs[k] = H[(size_t)k*NBL + b];
  __syncthreads();
  float mean = scal[1];
  int e0 = b*CH, e1 = min(e0 + CH, E2);
  for (int e = e0 + threadIdx.x; e < e1; e += 256){
    int d, s; float a;
    if (e < N_EDGES){ d = dst[e]; s = src[e]; a = ea[e]; }
    else { d = s = e - N_EDGES; a = mean; }
    int pos = atomicAdd(&lofs[d >> 7], 1);
    bpack[pos] = make_int2(s | ((d & 127) << 16), __float_as_int(a));
  }
}

// ---- layer 1: h1h(fp16) = x@W1, as1p/ad1p (padded 8) ----
__global__ __launch_bounds__(320) void k_h1(const float* __restrict__ x, const float* __restrict__ W1,
                    const float* __restrict__ as1w, const float* __restrict__ ad1w,
                    __half* __restrict__ h1h, float* __restrict__ as1p, float* __restrict__ ad1p){
  __shared__ float sW[5*F1];
  for (int k = threadIdx.x; k < 5*F1; k += 320) sW[k] = W1[k];
  __syncthreads();
  int nl = threadIdx.x / 80;
  int c  = threadIdx.x - nl*80;
  int n  = blockIdx.x*4 + nl;
  int c0 = 2*c;
  float hv0 = 0.f, hv1 = 0.f;
  #pragma unroll
  for (int f = 0; f < 5; f++){
    float xv = x[n*5 + f];
    hv0 += xv * sW[f*F1 + c0];
    hv1 += xv * sW[f*F1 + c0 + 1];
  }
  ((__half2*)h1h)[n*80 + c] = __floats2half2_rn(hv0, hv1);
  float vs = hv0*as1w[c0] + hv1*as1w[c0+1];
  float vd = hv0*ad1w[c0] + hv1*ad1w[c0+1];
  #pragma unroll
  for (int m = 8; m >= 1; m >>= 1){
    vs += __shfl_xor(vs, m, 64);
    vd += __shfl_xor(vd, m, 64);
  }
  if ((c & 15) == 0){
    int h = c >> 4;
    as1p[n*8 + h] = vs;
    ad1p[n*8 + h] = vd;
  }
}

// ---- pass 3: per-bucket fine sort FUSED with layer-1 softmax stats (alpha in fp16) ----
__global__ __launch_bounds__(256) void k_final2(const int* __restrict__ bstart,
                        const int2* __restrict__ bpack,
                        const float* __restrict__ as1p, const float* __restrict__ ad1p,
                        const float* __restrict__ scal,
                        int* __restrict__ offs, int* __restrict__ csrc, float* __restrict__ cea,
                        __half* __restrict__ alpha, float* __restrict__ iden1){
  __shared__ int cnt[128], cur[128];
  __shared__ float denL[128*HEADS];
  __shared__ float adL [128*HEADS];
  int k = blockIdx.x, t = threadIdx.x;
  int base = k*128;
  if (t < 128) cnt[t] = 0;
  for (int i = t; i < 128*HEADS; i += 256){
    int node = base + i/HEADS;
    adL[i] = (node < N_NODES) ? ad1p[node*8 + i%HEADS] : 0.f;
    denL[i] = 0.f;
  }
  __syncthreads();
  int r0 = bstart[k], r1 = bstart[k + 1];
  for (int j = r0 + t; j < r1; j += 256) atomicAdd(&cnt[(bpack[j].x >> 16) & 127], 1);
  __syncthreads();
  if (t == 0){
    int run = 0;
    for (int i = 0; i < 128; i++){ int c = cnt[i]; cnt[i] = run; cur[i] = run; run += c; }
  }
  __syncthreads();
  if (t < 128){
    int n = base + t;
    if (n < N_NODES) offs[n] = r0 + cnt[t];
  }
  float wd[HEADS];
  #pragma unroll
  for (int h = 0; h < HEADS; h++) wd[h] = scal[2 + h];
  for (int j = r0 + t; j < r1; j += 256){
    int2 v = bpack[j];
    int s = v.x & 0xFFFF, loc = (v.x >> 16) & 127;
    float ea = __int_as_float(v.y);
    int pos = r0 + atomicAdd(&cur[loc], 1);
    csrc[pos] = s;
    cea[pos]  = ea;
    float4 g4 = *(const float4*)(as1p + s*8);
    float g5 = as1p[s*8 + 4];
    float g[HEADS] = {g4.x, g4.y, g4.z, g4.w, g5};
    #pragma unroll
    for (int h = 0; h < HEADS; h++){
      float lg = g[h] + adL[loc*HEADS + h] + ea*wd[h];
      lg = fmaxf(lg, 0.2f*lg);
      lg = fminf(lg, 10.f);          // exp(10)=22026 fits fp16; logits ~N(0,2) never clamp
      float p = __expf(lg);
      alpha[(size_t)h*E2 + pos] = __float2half(p);
      atomicAdd(&denL[loc*HEADS + h], p);
    }
  }
  __syncthreads();
  for (int i = t; i < 128*HEADS; i += 256){
    int node = base + i/HEADS;
    if (node < N_NODES) iden1[node*8 + i%HEADS] = 1.f/(denL[i] + 1e-16f);
  }
}

// ---- layer 1 aggregate: pure FMA gather, unroll 8, fp16 alpha -> x2h(fp16) ----
__global__ __launch_bounds__(320) void k_agg1(const int* __restrict__ offs, const int* __restrict__ csrc,
                      const __half* __restrict__ alpha, const float* __restrict__ iden1,
                      const __half* __restrict__ h1h,
                      const float* __restrict__ b1, __half* __restrict__ x2h){
  int nl = threadIdx.x / 80;
  int c  = threadIdx.x - nl*80;
  int n  = blockIdx.x*4 + nl;
  int h  = c >> 4;
  const __half* aph = alpha + (size_t)h*E2;
  const __half2* h12 = (const __half2*)h1h;
  int j0 = offs[n], j1 = offs[n + 1];
  float acc0 = 0.f, acc1 = 0.f;
  int j = j0;
  int jal = min(j1, (j0 + 3) & ~3);
  for (; j < jal; ++j){
    int s = csrc[j];
    float a = __half2float(aph[j]);
    float2 f = __half22float2(h12[(size_t)s*80 + c]);
    acc0 += a*f.x; acc1 += a*f.y;
  }
  for (; j + 7 < j1; j += 8){
    int4   sa = *(const int4*)(csrc + j);
    int4   sb = *(const int4*)(csrc + j + 4);
    union { uint2 u; __half2 h[2]; } UA; UA.u = *(const uint2*)(aph + j);
    union { uint2 u; __half2 h[2]; } UB; UB.u = *(const uint2*)(aph + j + 4);
    float2 A01 = __half22float2(UA.h[0]);
    float2 A23 = __half22float2(UA.h[1]);
    float2 A45 = __half22float2(UB.h[0]);
    float2 A67 = __half22float2(UB.h[1]);
    float2 f0 = __half22float2(h12[(size_t)sa.x*80 + c]);
    float2 f1 = __half22float2(h12[(size_t)sa.y*80 + c]);
    float2 f2 = __half22float2(h12[(size_t)sa.z*80 + c]);
    float2 f3 = __half22float2(h12[(size_t)sa.w*80 + c]);
    float2 f4 = __half22float2(h12[(size_t)sb.x*80 + c]);
    float2 f5 = __half22float2(h12[(size_t)sb.y*80 + c]);
    float2 f6 = __half22float2(h12[(size_t)sb.z*80 + c]);
    float2 f7 = __half22float2(h12[(size_t)sb.w*80 + c]);
    acc0 += A01.x*f0.x; acc1 += A01.x*f0.y;
    acc0 += A01.y*f1.x; acc1 += A01.y*f1.y;
    acc0 += A23.x*f2.x; acc1 += A23.x*f2.y;
    acc0 += A23.y*f3.x; acc1 += A23.y*f3.y;
    acc0 += A45.x*f4.x; acc1 += A45.x*f4.y;
    acc0 += A45.y*f5.x; acc1 += A45.y*f5.y;
    acc0 += A67.x*f6.x; acc1 += A67.x*f6.y;
    acc0 += A67.y*f7.x; acc1 += A67.y*f7.y;
  }
  for (; j + 3 < j1; j += 4){
    int4   ss = *(const int4*)(csrc + j);
    union { uint2 u; __half2 h[2]; } UA; UA.u = *(const uint2*)(aph + j);
    float2 A01 = __half22float2(UA.h[0]);
    float2 A23 = __half22float2(UA.h[1]);
    float2 f0 = __half22float2(h12[(size_t)ss.x*80 + c]);
    float2 f1 = __half22float2(h12[(size_t)ss.y*80 + c]);
    float2 f2 = __half22float2(h12[(size_t)ss.z*80 + c]);
    float2 f3 = __half22float2(h12[(size_t)ss.w*80 + c]);
    acc0 += A01.x*f0.x; acc1 += A01.x*f0.y;
    acc0 += A01.y*f1.x; acc1 += A01.y*f1.y;
    acc0 += A23.x*f2.x; acc1 += A23.x*f2.y;
    acc0 += A23.y*f3.x; acc1 += A23.y*f3.y;
  }
  for (; j < j1; ++j){
    int s = csrc[j];
    float a = __half2float(aph[j]);
    float2 f = __half22float2(h12[(size_t)s*80 + c]);
    acc0 += a*f.x; acc1 += a*f.y;
  }
  float inv = iden1[n*8 + h];
  float v0 = fmaxf(acc0*inv + b1[2*c],     0.f);
  float v1 = fmaxf(acc1*inv + b1[2*c + 1], 0.f);
  ((__half2*)x2h)[(size_t)n*80 + c] = __floats2half2_rn(v0, v1);
}

// ---- layer 2: h2 = x2h@W2 -> packed fp16 G16 ([0..4]=h2, [5..9]=as2) + ad2p ----
__global__ __launch_bounds__(256) void k_h2(const __half* __restrict__ x2h, const float* __restrict__ W2,
                    const float* __restrict__ asw2, const float* __restrict__ adw2,
                    __half* __restrict__ G16, float* __restrict__ ad2p){
  __shared__ float sW[F1*HEADS];
  for (int k = threadIdx.x; k < F1*HEADS; k += 256) sW[k] = W2[k];
  __syncthreads();
  int w = threadIdx.x >> 6, l = threadIdx.x & 63;
  int n = blockIdx.x*4 + w;
  const __half2* x22 = (const __half2*)x2h;
  float acc[HEADS] = {0.f, 0.f, 0.f, 0.f, 0.f};
  for (int k2 = l; k2 < 80; k2 += 64){
    float2 f = __half22float2(x22[(size_t)n*80 + k2]);
    #pragma unroll
    for (int h = 0; h < HEADS; h++)
      acc[h] += f.x * sW[(2*k2)*HEADS + h] + f.y * sW[(2*k2+1)*HEADS + h];
  }
  #pragma unroll
  for (int m = 1; m < 64; m <<= 1){
    #pragma unroll
    for (int h = 0; h < HEADS; h++) acc[h] += __shfl_xor(acc[h], m, 64);
  }
  if (l == 0){
    #pragma unroll
    for (int h = 0; h < HEADS; h++){
      G16[(size_t)n*16 + h]     = __float2half(acc[h]);
      G16[(size_t)n*16 + 5 + h] = __float2half(acc[h] * asw2[h]);
      ad2p[n*8 + h]             = acc[h] * adw2[h];
    }
    #pragma unroll
    for (int z = 10; z < 16; z++) G16[(size_t)n*16 + z] = __float2half(0.f);
  }
}

// ---- layer 2: wave-per-node single-sweep softmax aggregate + mean + linear + sigmoid ----
__global__ __launch_bounds__(256) void k_agg2(const int* __restrict__ offs, const int* __restrict__ csrc,
                      const float* __restrict__ cea,
                      const __half* __restrict__ G16, const float* __restrict__ ad2p,
                      const float* __restrict__ scal,
                      const float* __restrict__ b2, const float* __restrict__ Wlin,
                      float* __restrict__ out){
  int w = threadIdx.x >> 6, l = threadIdx.x & 63;
  int n = blockIdx.x*4 + w;
  float adn[HEADS], wd[HEADS];
  #pragma unroll
  for (int h = 0; h < HEADS; h++){ adn[h] = ad2p[n*8 + h]; wd[h] = scal[7 + h]; }
  int j0 = offs[n], j1 = offs[n + 1];

  float den[HEADS] = {0,0,0,0,0};
  float ac[HEADS]  = {0,0,0,0,0};
  for (int j = j0 + l; j < j1; j += 64){
    int s = csrc[j];
    float c = cea[j];
    const __half* gs = G16 + (size_t)s*16;
    union { uint4 u; __half2 h[4]; } U; U.u = *(const uint4*)gs;
    union { uint2 u; __half2 h[2]; } V; V.u = *(const uint2*)(gs + 8);
    float2 p01 = __half22float2(U.h[0]);
    float2 p23 = __half22float2(U.h[1]);
    float2 p45 = __half22float2(U.h[2]);
    float2 p67 = __half22float2(U.h[3]);
    float2 p89 = __half22float2(V.h[0]);
    float hv[HEADS] = {p01.x, p01.y, p23.x, p23.y, p45.x};
    float av[HEADS] = {p45.y, p67.x, p67.y, p89.x, p89.y};
    #pragma unroll
    for (int h = 0; h < HEADS; h++){
      float lg = av[h] + adn[h] + c*wd[h];
      lg = fmaxf(lg, 0.2f*lg);
      lg = fminf(lg, 50.f);
      float p = __expf(lg);
      den[h] += p;
      ac[h]  += p * hv[h];
    }
  }
  #pragma unroll
  for (int m = 1; m < 64; m <<= 1){
    #pragma unroll
    for (int h = 0; h < HEADS; h++){
      den[h] += __shfl_xor(den[h], m, 64);
      ac[h]  += __shfl_xor(ac[h], m, 64);
    }
  }
  if (l == 0){
    float v = 0.f;
    #pragma unroll
    for (int h = 0; h < HEADS; h++) v += ac[h] / (den[h] + 1e-16f);
    v = v * (1.f/HEADS) + b2[0];
    v *= Wlin[0];
    out[n] = 1.f / (1.f + __expf(-v));
  }
}

extern "C" void kernel_launch(void* const* d_in, const int* in_sizes, int n_in,
                              void* d_out, int out_size, void* d_ws, size_t ws_size,
                              hipStream_t stream) {
  const float* x    = (const float*)d_in[0];
  const float* ea   = (const float*)d_in[1];
  const int*   src  = (const int*)d_in[2];
  const int*   dst  = (const int*)d_in[3];
  const float* W1   = (const float*)d_in[4];
  const float* as1w = (const float*)d_in[5];
  const float* ad1w = (const float*)d_in[6];
  const float* We1  = (const float*)d_in[7];
  const float* ae1  = (const float*)d_in[8];
  const float* b1   = (const float*)d_in[9];
  const float* W2   = (const float*)d_in[10];
  const float* as2w = (const float*)d_in[11];
  const float* ad2w = (const float*)d_in[12];
  const float* We2  = (const float*)d_in[13];
  const float* ae2  = (const float*)d_in[14];
  const float* b2   = (const float*)d_in[15];
  const float* Wlin = (const float*)d_in[16];

  char* ws = (char*)d_ws;
  float* scal   = (float*)(ws + OFF_SCAL);
  int*   H      = (int*)  (ws + OFF_H);
  int*   part   = (int*)  (ws + OFF_PART);
  int*   ppref  = (int*)  (ws + OFF_PPREF);
  int*   bstart = (int*)  (ws + OFF_BST);
  int*   offs   = (int*)  (ws + OFF_OFFS);
  int2*  bpack  = (int2*) (ws + OFF_BPACK);
  int*   csrc   = (int*)  (ws + OFF_CSRC);
  float* cea    = (float*)(ws + OFF_CEA);
  float* as1p   = (float*)(ws + OFF_AS1P);
  float* ad1p   = (float*)(ws + OFF_AD1P);
  float* iden1  = (float*)(ws + OFF_IDEN1);
  __half* G16   = (__half*)(ws + OFF_G16);
  float* ad2p   = (float*)(ws + OFF_AD2P);
  __half* h1h   = (__half*)(ws + OFF_H1H);
  __half* x2h   = (__half*)(ws + OFF_X2H);
  __half* alpha = (__half*)(ws + OFF_ALPH);
  float* outp   = (float*)d_out;

  hipMemsetAsync(scal, 0, 64*sizeof(float), stream);

  k_h1     <<<N_NODES/4, 320, 0, stream>>>(x, W1, as1w, ad1w, h1h, as1p, ad1p);
  k_hist   <<<NBL, 256, 0, stream>>>(dst, ea, H, scal);
  k_prep   <<<1, 64, 0, stream>>>(We1, ae1, We2, ae2, scal);
  k_s1     <<<MC, 256, 0, stream>>>(H, part);
  k_s2     <<<1, 256, 0, stream>>>(part, ppref, offs, bstart);
  k_s3     <<<MC, 256, 0, stream>>>(H, ppref, bstart);
  k_scat   <<<NBL, 256, 0, stream>>>(src, dst, ea, scal, H, bpack);
  k_final2 <<<NBK, 256, 0, stream>>>(bstart, bpack, as1p, ad1p, scal, offs, csrc, cea, alpha, iden1);

  k_agg1   <<<N_NODES/4, 320, 0, stream>>>(offs, csrc, alpha, iden1, h1h, b1, x2h);
  k_h2     <<<N_NODES/4, 256, 0, stream>>>(x2h, W2, as2w, ad2w, G16, ad2p);
  k_agg2   <<<N_NODES/4, 256, 0, stream>>>(offs, csrc, cea, G16, ad2p, scal, b2, Wlin, outp);
}